// Round 12
// baseline (725.295 us; speedup 1.0000x reference)
//
#include <hip/hip_runtime.h>
#include <math.h>

// Problem constants: x(256,8192) b,q,e(8192) M(100,8192) out(256,100)
#define NN 8192
#define BB 256
#define CC 100
#define MAX_ITERS 4096

// ---------------------------------------------------------------------------
// Fire kernel, RPT=1: thread = (row i, column j). Light body so the trap
// column's serial tail (t_a > 2048, measured r11) costs ~24 cyc/iter instead
// of ~153. Locked reference flavor: hoisted IEEE f32 reciprocals
// rb=1.0f/b, rob=1.0f/(1-b); m' = (m<b ? m : 1-m) * (m<b ? rb : rob).
//
// Cycle fast-forward (bit-exact): if m_new equals m (1-cycle: absorption at
// 0 / -inf / rounding fixed point) or m_prev (2-cycle) while the element is
// still active, every future value repeats values already survived -> the
// element can never fire -> k += remaining iterations, exit. The current
// iteration is processed normally BEFORE the fast-forward, preserving the
// reference's exact k.
// ---------------------------------------------------------------------------
__global__ __launch_bounds__(256) void fire_kernel(
    const float* __restrict__ x, const float* __restrict__ bmap,
    const float* __restrict__ qini, const float* __restrict__ eps,
    float* __restrict__ kout)
{
    const int j = blockIdx.x * 256 + threadIdx.x;   // column
    const int i = blockIdx.y;                       // row

    const float bv  = bmap[j];
    const float qv  = qini[j];
    const float ev  = eps[j];
    const float xv  = x[(size_t)i * NN + j];
    const float lov = xv - ev;          // exact f32 subs, same bits as ref
    const float hiv = xv + ev;
    const float obv = 1.0f - bv;        // exact (Sterbenz)
    const float rb  = 1.0f / bv;        // hoisted IEEE f32 reciprocals (ref flavor)
    const float rob = 1.0f / obv;

    float m  = qv;
    float mp = qv;                      // m_{t-1} for 2-cycle check
    int   kk = 1;
    bool  a  = (qv != 0.0f);            // q==0 never fires

    for (int it = 0; a && it < MAX_ITERS; ++it) {
        const bool  lt = (m < bv);
        const float mn = (lt ? m : (1.0f - m)) * (lt ? rb : rob);  // ref flavor
        const bool cyc = (mn == m) || (mn == mp);
        mp = m;
        m  = mn;
        const bool o = (m < lov) || (m > hiv);
        kk += (a && o) ? 1 : 0;
        a = a && o;
        if (cyc && a) {                 // periodic & still active -> never fires
            kk += MAX_ITERS - 1 - it;
            break;
        }
    }

    kout[(size_t)i * NN + j] = (float)kk;
}

// ---------------------------------------------------------------------------
// Norm kernel: blocks 0..255 -> ||k[i]||, blocks 256..355 -> ||M[c]||.
// f64 accumulation. norms[row]=max(sqrt,1e-8).
// ---------------------------------------------------------------------------
__global__ __launch_bounds__(256) void norm_kernel(
    const float* __restrict__ k, const float* __restrict__ M,
    float* __restrict__ norms)
{
    __shared__ double red[4];
    const int row = blockIdx.x;
    const float* src = (row < BB) ? (k + (size_t)row * NN)
                                  : (M + (size_t)(row - BB) * NN);
    double s = 0.0;
    for (int j = threadIdx.x * 4; j < NN; j += 1024) {
        const float4 v = *(const float4*)(src + j);
        s += (double)v.x * v.x + (double)v.y * v.y
           + (double)v.z * v.z + (double)v.w * v.w;
    }
    #pragma unroll
    for (int off = 32; off; off >>= 1) s += __shfl_down(s, off, 64);
    const int wid = threadIdx.x >> 6, lane = threadIdx.x & 63;
    if (lane == 0) red[wid] = s;
    __syncthreads();
    if (threadIdx.x == 0)
        norms[row] = fmaxf((float)sqrt(red[0] + red[1] + red[2] + red[3]), 1e-8f);
}

// ---------------------------------------------------------------------------
// Logits kernel: block = (row-quad, class-half). 4 k rows in registers
// (32 float4/thread), M streamed once per block from L2 (halves M traffic
// vs 2-row blocking). Per-class accumulation order identical to r11.
// ---------------------------------------------------------------------------
__global__ __launch_bounds__(256) void logits_kernel(
    const float* __restrict__ k, const float* __restrict__ M,
    const float* __restrict__ norms, float* __restrict__ out)
{
    __shared__ float red[4][4];
    const int rq = blockIdx.x >> 1;       // 0..63 row-quad
    const int ch = blockIdx.x & 1;        // 0..1 class half
    const int i0 = rq * 4;
    const int tid = threadIdx.x;

    float4 kr[4][8];
    #pragma unroll
    for (int r = 0; r < 4; ++r)
        #pragma unroll
        for (int s = 0; s < 8; ++s)
            kr[r][s] = *(const float4*)(k + (size_t)(i0 + r) * NN + s * 1024 + tid * 4);
    float rn[4];
    #pragma unroll
    for (int r = 0; r < 4; ++r) rn[r] = norms[i0 + r];

    for (int c = ch * 50; c < ch * 50 + 50; ++c) {
        const float4* Mp = (const float4*)(M + (size_t)c * NN);
        float acc[4] = {0.0f, 0.0f, 0.0f, 0.0f};
        #pragma unroll
        for (int s = 0; s < 8; ++s) {
            const float4 mv = Mp[s * 256 + tid];
            #pragma unroll
            for (int r = 0; r < 4; ++r)
                acc[r] += kr[r][s].x * mv.x + kr[r][s].y * mv.y
                        + kr[r][s].z * mv.z + kr[r][s].w * mv.w;
        }
        #pragma unroll
        for (int off = 32; off; off >>= 1)
            #pragma unroll
            for (int r = 0; r < 4; ++r) acc[r] += __shfl_down(acc[r], off, 64);
        const int wid = tid >> 6, lane = tid & 63;
        if (lane == 0)
            #pragma unroll
            for (int r = 0; r < 4; ++r) red[wid][r] = acc[r];
        __syncthreads();
        if (tid < 4) {   // thread r writes row i0+r
            const float d  = red[0][tid] + red[1][tid] + red[2][tid] + red[3][tid];
            const float mn = norms[BB + c];
            out[(size_t)(i0 + tid) * CC + c] = d / (rn[tid] * mn);
        }
        __syncthreads();
    }
}

// ===========================================================================
// FALLBACK: round-10 fused kernel, verbatim (proven green), used only if
// ws_size is too small for the k matrix.
// ===========================================================================
__global__ __launch_bounds__(256) void gls_fused_kernel(
    const float* __restrict__ x, const float* __restrict__ bmap,
    const float* __restrict__ qini, const float* __restrict__ eps,
    const float* __restrict__ M, float* __restrict__ out)
{
    __shared__ float k_lds[NN];
    __shared__ double redsh[4];

    const int i   = blockIdx.x;
    const int tid = threadIdx.x;
    const int wid = tid >> 6, lane = tid & 63;

    double sumsq = 0.0;
    for (int s = 0; s < 32; ++s) {
        const int j = tid + 256 * s;
        const float bv = bmap[j];
        const float qv = qini[j];
        const float ev = eps[j];
        const float xv = x[(size_t)i * NN + j];
        const float lov = xv - ev;
        const float hiv = xv + ev;
        const float obv = 1.0f - bv;
        const float rb  = 1.0f / bv;
        const float rob = 1.0f / obv;

        float m  = qv;
        float kk = 1.0f;
        bool  a  = (qv != 0.0f);
        for (int it = 0; a && it < MAX_ITERS; ++it) {
            const bool  lt  = (m < bv);
            const float num = lt ? m  : (1.0f - m);
            const float r   = lt ? rb : rob;
            m = num * r;
            a = (m < lov) || (m > hiv);
            kk += a ? 1.0f : 0.0f;
        }
        k_lds[j] = kk;
        sumsq += (double)kk * (double)kk;
    }

    #pragma unroll
    for (int off = 32; off; off >>= 1) sumsq += __shfl_down(sumsq, off, 64);
    if (lane == 0) redsh[wid] = sumsq;
    __syncthreads();
    const double rn = fmax(sqrt(redsh[0] + redsh[1] + redsh[2] + redsh[3]), 1e-8);

    for (int cc2 = 0; cc2 < 25; ++cc2) {
        const int c = wid * 25 + cc2;
        const float4* Mp = (const float4*)(M + (size_t)c * NN);
        double dot = 0.0, msq = 0.0;
        #pragma unroll 4
        for (int s = 0; s < 32; ++s) {
            const float4 mv = Mp[lane + 64 * s];
            const float4 kv = *(const float4*)(&k_lds[4 * (lane + 64 * s)]);
            dot += (double)kv.x * (double)mv.x + (double)kv.y * (double)mv.y
                 + (double)kv.z * (double)mv.z + (double)kv.w * (double)mv.w;
            msq += (double)mv.x * (double)mv.x + (double)mv.y * (double)mv.y
                 + (double)mv.z * (double)mv.z + (double)mv.w * (double)mv.w;
        }
        #pragma unroll
        for (int off = 32; off; off >>= 1) {
            dot += __shfl_down(dot, off, 64);
            msq += __shfl_down(msq, off, 64);
        }
        if (lane == 0) {
            const double mn = fmax(sqrt(msq), 1e-8);
            out[(size_t)i * CC + c] = (float)(dot / (rn * mn));
        }
    }
}

// ---------------------------------------------------------------------------
extern "C" void kernel_launch(void* const* d_in, const int* in_sizes, int n_in,
                              void* d_out, int out_size, void* d_ws, size_t ws_size,
                              hipStream_t stream) {
    const float* x = (const float*)d_in[0];  // (256, 8192)
    const float* b = (const float*)d_in[1];  // (8192,)
    const float* q = (const float*)d_in[2];  // (8192,)
    const float* e = (const float*)d_in[3];  // (8192,)
    const float* M = (const float*)d_in[4];  // (100, 8192)
    float* out = (float*)d_out;              // (256, 100)

    const size_t need = (size_t)BB * NN * sizeof(float) + (BB + CC) * sizeof(float);
    if (ws_size >= need) {
        float* kbuf  = (float*)d_ws;
        float* norms = kbuf + (size_t)BB * NN;
        fire_kernel<<<dim3(32, 256), dim3(256), 0, stream>>>(x, b, q, e, kbuf);
        norm_kernel<<<dim3(BB + CC), dim3(256), 0, stream>>>(kbuf, M, norms);
        logits_kernel<<<dim3(128), dim3(256), 0, stream>>>(kbuf, M, norms, out);
    } else {
        gls_fused_kernel<<<dim3(BB), dim3(256), 0, stream>>>(x, b, q, e, M, out);
    }
}

// Round 13
// 175.675 us; speedup vs baseline: 4.1286x; 4.1286x over previous
//
#include <hip/hip_runtime.h>
#include <math.h>

// Problem constants: x(256,8192) b,q,e(8192) M(100,8192) out(256,100)
#define NN 8192
#define BB 256
#define CC 100
#define MAX_ITERS 4096

// ---------------------------------------------------------------------------
// Fire kernel, wave = one column x 64 rows (lane = row). The map trajectory
// depends only on the column -> it is WAVE-UNIFORM: computed once per
// iteration (~6 VALU), shared by 64 per-lane band checks. Healthy columns
// exit at their own row-max (~45-70 iters); heavy-tail columns (~1.5%,
// k~300-1000, measured r11/r12) don't contaminate other columns' waves; the
// trap column runs its 4096 iters as a ~30 us critical path overlapped with
// all other work.
//
// Locked reference flavor (r10): hoisted IEEE f32 reciprocals rb=1.0f/b,
// rob=1.0f/(1-b); m' = (m<b ? m : 1-m) * (m<b ? rb : rob); separate sub and
// mul (no FMA contraction -- changes bits). lo=x-e, hi=x+e exact f32 subs.
//
// Cycle fast-forward (bit-exact, wave-uniform): if m_new equals m (1-cycle),
// m_prev (2-cycle), or the Brent anchor (any cycle with entry+period within
// the doubling window), every future value repeats values all surviving
// lanes already missed -> they can never fire -> k += remaining, exit.
// The current iteration is processed normally BEFORE the fast-forward.
// ---------------------------------------------------------------------------
__global__ __launch_bounds__(256) void fire_kernel(
    const float* __restrict__ x, const float* __restrict__ bmap,
    const float* __restrict__ qini, const float* __restrict__ eps,
    float* __restrict__ kout)
{
    const int j    = blockIdx.x;              // column (one per block)
    const int lane = threadIdx.x & 63;
    const int row  = (threadIdx.x & ~63) + lane;   // wave w covers rows 64w..64w+63

    const float bv  = bmap[j];                // uniform -> scalar regs
    const float qv  = qini[j];
    const float ev  = eps[j];
    const float obv = 1.0f - bv;              // exact (Sterbenz)
    const float rb  = 1.0f / bv;              // hoisted IEEE f32 reciprocals
    const float rob = 1.0f / obv;

    const float xv  = x[(size_t)row * NN + j];     // scattered dword load
    const float lov = xv - ev;                // exact f32 subs, same bits as ref
    const float hiv = xv + ev;

    float m = qv, mp = qv, anchor = qv;       // trajectory state (uniform)
    int   window = 1, steps = 0;
    int   kk = 1;
    bool  a  = (qv != 0.0f);                  // q==0: whole column never fires

    for (int it = 0; it < MAX_ITERS; ++it) {
        // --- map step (uniform; plain sub/mul/select, ref flavor) ---
        const bool  lt = (m < bv);
        const float pa = m * rb;
        const float t1 = 1.0f - m;
        const float pb = t1 * rob;
        const float mn2 = lt ? pa : pb;
        const bool  cyc = (mn2 == m) || (mn2 == mp) || (mn2 == anchor);
        mp = m;
        m  = mn2;
        if (++steps == window) { anchor = m; window <<= 1; steps = 0; }

        // --- per-lane band check ---
        const bool o = (m < lov) || (m > hiv);
        kk += (a && o) ? 1 : 0;
        a = a && o;

        if (__ballot(a) == 0ull) break;       // all 64 rows fired
        if (cyc) {                            // uniform: trajectory repeats ->
            kk += a ? (MAX_ITERS - 1 - it) : 0;   // survivors never fire
            break;
        }
    }

    kout[(size_t)row * NN + j] = (float)kk;   // scattered dword store
}

// ---------------------------------------------------------------------------
// Norm kernel (r12 verbatim): blocks 0..255 -> ||k[i]||, 256..355 -> ||M[c]||.
// ---------------------------------------------------------------------------
__global__ __launch_bounds__(256) void norm_kernel(
    const float* __restrict__ k, const float* __restrict__ M,
    float* __restrict__ norms)
{
    __shared__ double red[4];
    const int row = blockIdx.x;
    const float* src = (row < BB) ? (k + (size_t)row * NN)
                                  : (M + (size_t)(row - BB) * NN);
    double s = 0.0;
    for (int j = threadIdx.x * 4; j < NN; j += 1024) {
        const float4 v = *(const float4*)(src + j);
        s += (double)v.x * v.x + (double)v.y * v.y
           + (double)v.z * v.z + (double)v.w * v.w;
    }
    #pragma unroll
    for (int off = 32; off; off >>= 1) s += __shfl_down(s, off, 64);
    const int wid = threadIdx.x >> 6, lane = threadIdx.x & 63;
    if (lane == 0) red[wid] = s;
    __syncthreads();
    if (threadIdx.x == 0)
        norms[row] = fmaxf((float)sqrt(red[0] + red[1] + red[2] + red[3]), 1e-8f);
}

// ---------------------------------------------------------------------------
// Logits kernel (r12 verbatim): block = (row-quad, class-half); 4 k rows in
// registers, M streamed from L2.
// ---------------------------------------------------------------------------
__global__ __launch_bounds__(256) void logits_kernel(
    const float* __restrict__ k, const float* __restrict__ M,
    const float* __restrict__ norms, float* __restrict__ out)
{
    __shared__ float red[4][4];
    const int rq = blockIdx.x >> 1;
    const int ch = blockIdx.x & 1;
    const int i0 = rq * 4;
    const int tid = threadIdx.x;

    float4 kr[4][8];
    #pragma unroll
    for (int r = 0; r < 4; ++r)
        #pragma unroll
        for (int s = 0; s < 8; ++s)
            kr[r][s] = *(const float4*)(k + (size_t)(i0 + r) * NN + s * 1024 + tid * 4);
    float rn[4];
    #pragma unroll
    for (int r = 0; r < 4; ++r) rn[r] = norms[i0 + r];

    for (int c = ch * 50; c < ch * 50 + 50; ++c) {
        const float4* Mp = (const float4*)(M + (size_t)c * NN);
        float acc[4] = {0.0f, 0.0f, 0.0f, 0.0f};
        #pragma unroll
        for (int s = 0; s < 8; ++s) {
            const float4 mv = Mp[s * 256 + tid];
            #pragma unroll
            for (int r = 0; r < 4; ++r)
                acc[r] += kr[r][s].x * mv.x + kr[r][s].y * mv.y
                        + kr[r][s].z * mv.z + kr[r][s].w * mv.w;
        }
        #pragma unroll
        for (int off = 32; off; off >>= 1)
            #pragma unroll
            for (int r = 0; r < 4; ++r) acc[r] += __shfl_down(acc[r], off, 64);
        const int wid = tid >> 6, lane = tid & 63;
        if (lane == 0)
            #pragma unroll
            for (int r = 0; r < 4; ++r) red[wid][r] = acc[r];
        __syncthreads();
        if (tid < 4) {
            const float d  = red[0][tid] + red[1][tid] + red[2][tid] + red[3][tid];
            const float mn = norms[BB + c];
            out[(size_t)(i0 + tid) * CC + c] = d / (rn[tid] * mn);
        }
        __syncthreads();
    }
}

// ===========================================================================
// FALLBACK: round-10 fused kernel, verbatim (proven green), used only if
// ws_size is too small for the k matrix.
// ===========================================================================
__global__ __launch_bounds__(256) void gls_fused_kernel(
    const float* __restrict__ x, const float* __restrict__ bmap,
    const float* __restrict__ qini, const float* __restrict__ eps,
    const float* __restrict__ M, float* __restrict__ out)
{
    __shared__ float k_lds[NN];
    __shared__ double redsh[4];

    const int i   = blockIdx.x;
    const int tid = threadIdx.x;
    const int wid = tid >> 6, lane = tid & 63;

    double sumsq = 0.0;
    for (int s = 0; s < 32; ++s) {
        const int j = tid + 256 * s;
        const float bv = bmap[j];
        const float qv = qini[j];
        const float ev = eps[j];
        const float xv = x[(size_t)i * NN + j];
        const float lov = xv - ev;
        const float hiv = xv + ev;
        const float obv = 1.0f - bv;
        const float rb  = 1.0f / bv;
        const float rob = 1.0f / obv;

        float m  = qv;
        float kk = 1.0f;
        bool  a  = (qv != 0.0f);
        for (int it = 0; a && it < MAX_ITERS; ++it) {
            const bool  lt  = (m < bv);
            const float num = lt ? m  : (1.0f - m);
            const float r   = lt ? rb : rob;
            m = num * r;
            a = (m < lov) || (m > hiv);
            kk += a ? 1.0f : 0.0f;
        }
        k_lds[j] = kk;
        sumsq += (double)kk * (double)kk;
    }

    #pragma unroll
    for (int off = 32; off; off >>= 1) sumsq += __shfl_down(sumsq, off, 64);
    if (lane == 0) redsh[wid] = sumsq;
    __syncthreads();
    const double rn = fmax(sqrt(redsh[0] + redsh[1] + redsh[2] + redsh[3]), 1e-8);

    for (int cc2 = 0; cc2 < 25; ++cc2) {
        const int c = wid * 25 + cc2;
        const float4* Mp = (const float4*)(M + (size_t)c * NN);
        double dot = 0.0, msq = 0.0;
        #pragma unroll 4
        for (int s = 0; s < 32; ++s) {
            const float4 mv = Mp[lane + 64 * s];
            const float4 kv = *(const float4*)(&k_lds[4 * (lane + 64 * s)]);
            dot += (double)kv.x * (double)mv.x + (double)kv.y * (double)mv.y
                 + (double)kv.z * (double)mv.z + (double)kv.w * (double)mv.w;
            msq += (double)mv.x * (double)mv.x + (double)mv.y * (double)mv.y
                 + (double)mv.z * (double)mv.z + (double)mv.w * (double)mv.w;
        }
        #pragma unroll
        for (int off = 32; off; off >>= 1) {
            dot += __shfl_down(dot, off, 64);
            msq += __shfl_down(msq, off, 64);
        }
        if (lane == 0) {
            const double mn = fmax(sqrt(msq), 1e-8);
            out[(size_t)i * CC + c] = (float)(dot / (rn * mn));
        }
    }
}

// ---------------------------------------------------------------------------
extern "C" void kernel_launch(void* const* d_in, const int* in_sizes, int n_in,
                              void* d_out, int out_size, void* d_ws, size_t ws_size,
                              hipStream_t stream) {
    const float* x = (const float*)d_in[0];  // (256, 8192)
    const float* b = (const float*)d_in[1];  // (8192,)
    const float* q = (const float*)d_in[2];  // (8192,)
    const float* e = (const float*)d_in[3];  // (8192,)
    const float* M = (const float*)d_in[4];  // (100, 8192)
    float* out = (float*)d_out;              // (256, 100)

    const size_t need = (size_t)BB * NN * sizeof(float) + (BB + CC) * sizeof(float);
    if (ws_size >= need) {
        float* kbuf  = (float*)d_ws;
        float* norms = kbuf + (size_t)BB * NN;
        fire_kernel<<<dim3(NN), dim3(256), 0, stream>>>(x, b, q, e, kbuf);
        norm_kernel<<<dim3(BB + CC), dim3(256), 0, stream>>>(kbuf, M, norms);
        logits_kernel<<<dim3(128), dim3(256), 0, stream>>>(kbuf, M, norms, out);
    } else {
        gls_fused_kernel<<<dim3(BB), dim3(256), 0, stream>>>(x, b, q, e, M, out);
    }
}

// Round 14
// 162.904 us; speedup vs baseline: 4.4523x; 1.0784x over previous
//
#include <hip/hip_runtime.h>
#include <math.h>

// Problem constants: x(256,8192) b,q,e(8192) M(100,8192) out(256,100)
#define NN 8192
#define BB 256
#define CC 100
#define MAX_ITERS 4096

// ---------------------------------------------------------------------------
// Fire kernel, wave = one column x 64 rows (lane = row). Map trajectory is
// wave-uniform; per-lane band checks. Slimmed body (~10 VALU/iter):
//  - Brent-anchor-only cycle detection (1 compare). Detection time does not
//    affect k: when m repeats a previously-seen value, all future values
//    were already survived by every still-active lane -> they can never
//    fire -> kk += remaining iterations (exact credit).
//  - kk update: a = a && in-band-complement; kk += a  (identical to
//    reference's act &= invalid; k += act).
// Locked reference flavor (r10): hoisted IEEE f32 reciprocals rb=1.0f/b,
// rob=1.0f/(1-b); m' = (m<b ? m*rb : (1-m)*rob) as separate sub/mul/select
// (no FMA contraction possible); lo=x-e, hi=x+e exact f32 subs.
// ---------------------------------------------------------------------------
__global__ __launch_bounds__(256) void fire_kernel(
    const float* __restrict__ x, const float* __restrict__ bmap,
    const float* __restrict__ qini, const float* __restrict__ eps,
    float* __restrict__ kout)
{
    const int j    = blockIdx.x;              // column (one per block)
    const int lane = threadIdx.x & 63;
    const int row  = (threadIdx.x & ~63) + lane;   // wave w covers rows 64w..64w+63

    const float bv  = bmap[j];                // uniform across the wave
    const float qv  = qini[j];
    const float ev  = eps[j];
    const float obv = 1.0f - bv;              // exact (Sterbenz)
    const float rb  = 1.0f / bv;              // hoisted IEEE f32 reciprocals
    const float rob = 1.0f / obv;

    const float xv  = x[(size_t)row * NN + j];     // scattered dword load (once)
    const float lov = xv - ev;                // exact f32 subs, same bits as ref
    const float hiv = xv + ev;

    float m = qv, anchor = qv;                // uniform trajectory state
    int   window = 1, steps = 0;
    int   kk = 1;
    bool  a  = (qv != 0.0f);                  // q==0: never fires

    for (int it = 0; it < MAX_ITERS; ++it) {
        // map step: both products independent, one select (short dep chain)
        const bool  lt = (m < bv);
        const float pa = m * rb;
        const float pb = (1.0f - m) * rob;
        m = lt ? pa : pb;

        const bool cyc = (m == anchor);       // Brent-only cycle probe
        if (++steps == window) { anchor = m; window <<= 1; steps = 0; }

        // band check: a_new = a && outside; k += a_new  (== ref semantics)
        const bool o = (m < lov) || (m > hiv);
        a = a && o;
        kk += a ? 1 : 0;

        if (__ballot(a) == 0ull) break;       // all 64 rows fired
        if (cyc) {                            // trajectory periodic ->
            kk += a ? (MAX_ITERS - 1 - it) : 0;   // survivors never fire (exact)
            break;
        }
    }

    kout[(size_t)row * NN + j] = (float)kk;   // scattered dword store (once)
}

// ---------------------------------------------------------------------------
// Norm kernel (r12 verbatim): blocks 0..255 -> ||k[i]||, 256..355 -> ||M[c]||.
// ---------------------------------------------------------------------------
__global__ __launch_bounds__(256) void norm_kernel(
    const float* __restrict__ k, const float* __restrict__ M,
    float* __restrict__ norms)
{
    __shared__ double red[4];
    const int row = blockIdx.x;
    const float* src = (row < BB) ? (k + (size_t)row * NN)
                                  : (M + (size_t)(row - BB) * NN);
    double s = 0.0;
    for (int j = threadIdx.x * 4; j < NN; j += 1024) {
        const float4 v = *(const float4*)(src + j);
        s += (double)v.x * v.x + (double)v.y * v.y
           + (double)v.z * v.z + (double)v.w * v.w;
    }
    #pragma unroll
    for (int off = 32; off; off >>= 1) s += __shfl_down(s, off, 64);
    const int wid = threadIdx.x >> 6, lane = threadIdx.x & 63;
    if (lane == 0) red[wid] = s;
    __syncthreads();
    if (threadIdx.x == 0)
        norms[row] = fmaxf((float)sqrt(red[0] + red[1] + red[2] + red[3]), 1e-8f);
}

// ---------------------------------------------------------------------------
// Logits kernel (r12 verbatim): block = (row-quad, class-half); 4 k rows in
// registers, M streamed from L2.
// ---------------------------------------------------------------------------
__global__ __launch_bounds__(256) void logits_kernel(
    const float* __restrict__ k, const float* __restrict__ M,
    const float* __restrict__ norms, float* __restrict__ out)
{
    __shared__ float red[4][4];
    const int rq = blockIdx.x >> 1;
    const int ch = blockIdx.x & 1;
    const int i0 = rq * 4;
    const int tid = threadIdx.x;

    float4 kr[4][8];
    #pragma unroll
    for (int r = 0; r < 4; ++r)
        #pragma unroll
        for (int s = 0; s < 8; ++s)
            kr[r][s] = *(const float4*)(k + (size_t)(i0 + r) * NN + s * 1024 + tid * 4);
    float rn[4];
    #pragma unroll
    for (int r = 0; r < 4; ++r) rn[r] = norms[i0 + r];

    for (int c = ch * 50; c < ch * 50 + 50; ++c) {
        const float4* Mp = (const float4*)(M + (size_t)c * NN);
        float acc[4] = {0.0f, 0.0f, 0.0f, 0.0f};
        #pragma unroll
        for (int s = 0; s < 8; ++s) {
            const float4 mv = Mp[s * 256 + tid];
            #pragma unroll
            for (int r = 0; r < 4; ++r)
                acc[r] += kr[r][s].x * mv.x + kr[r][s].y * mv.y
                        + kr[r][s].z * mv.z + kr[r][s].w * mv.w;
        }
        #pragma unroll
        for (int off = 32; off; off >>= 1)
            #pragma unroll
            for (int r = 0; r < 4; ++r) acc[r] += __shfl_down(acc[r], off, 64);
        const int wid = tid >> 6, lane = tid & 63;
        if (lane == 0)
            #pragma unroll
            for (int r = 0; r < 4; ++r) red[wid][r] = acc[r];
        __syncthreads();
        if (tid < 4) {
            const float d  = red[0][tid] + red[1][tid] + red[2][tid] + red[3][tid];
            const float mn = norms[BB + c];
            out[(size_t)(i0 + tid) * CC + c] = d / (rn[tid] * mn);
        }
        __syncthreads();
    }
}

// ===========================================================================
// FALLBACK: round-10 fused kernel, verbatim (proven green), used only if
// ws_size is too small for the k matrix.
// ===========================================================================
__global__ __launch_bounds__(256) void gls_fused_kernel(
    const float* __restrict__ x, const float* __restrict__ bmap,
    const float* __restrict__ qini, const float* __restrict__ eps,
    const float* __restrict__ M, float* __restrict__ out)
{
    __shared__ float k_lds[NN];
    __shared__ double redsh[4];

    const int i   = blockIdx.x;
    const int tid = threadIdx.x;
    const int wid = tid >> 6, lane = tid & 63;

    double sumsq = 0.0;
    for (int s = 0; s < 32; ++s) {
        const int j = tid + 256 * s;
        const float bv = bmap[j];
        const float qv = qini[j];
        const float ev = eps[j];
        const float xv = x[(size_t)i * NN + j];
        const float lov = xv - ev;
        const float hiv = xv + ev;
        const float obv = 1.0f - bv;
        const float rb  = 1.0f / bv;
        const float rob = 1.0f / obv;

        float m  = qv;
        float kk = 1.0f;
        bool  a  = (qv != 0.0f);
        for (int it = 0; a && it < MAX_ITERS; ++it) {
            const bool  lt  = (m < bv);
            const float num = lt ? m  : (1.0f - m);
            const float r   = lt ? rb : rob;
            m = num * r;
            a = (m < lov) || (m > hiv);
            kk += a ? 1.0f : 0.0f;
        }
        k_lds[j] = kk;
        sumsq += (double)kk * (double)kk;
    }

    #pragma unroll
    for (int off = 32; off; off >>= 1) sumsq += __shfl_down(sumsq, off, 64);
    if (lane == 0) redsh[wid] = sumsq;
    __syncthreads();
    const double rn = fmax(sqrt(redsh[0] + redsh[1] + redsh[2] + redsh[3]), 1e-8);

    for (int cc2 = 0; cc2 < 25; ++cc2) {
        const int c = wid * 25 + cc2;
        const float4* Mp = (const float4*)(M + (size_t)c * NN);
        double dot = 0.0, msq = 0.0;
        #pragma unroll 4
        for (int s = 0; s < 32; ++s) {
            const float4 mv = Mp[lane + 64 * s];
            const float4 kv = *(const float4*)(&k_lds[4 * (lane + 64 * s)]);
            dot += (double)kv.x * (double)mv.x + (double)kv.y * (double)mv.y
                 + (double)kv.z * (double)mv.z + (double)kv.w * (double)mv.w;
            msq += (double)mv.x * (double)mv.x + (double)mv.y * (double)mv.y
                 + (double)mv.z * (double)mv.z + (double)mv.w * (double)mv.w;
        }
        #pragma unroll
        for (int off = 32; off; off >>= 1) {
            dot += __shfl_down(dot, off, 64);
            msq += __shfl_down(msq, off, 64);
        }
        if (lane == 0) {
            const double mn = fmax(sqrt(msq), 1e-8);
            out[(size_t)i * CC + c] = (float)(dot / (rn * mn));
        }
    }
}

// ---------------------------------------------------------------------------
extern "C" void kernel_launch(void* const* d_in, const int* in_sizes, int n_in,
                              void* d_out, int out_size, void* d_ws, size_t ws_size,
                              hipStream_t stream) {
    const float* x = (const float*)d_in[0];  // (256, 8192)
    const float* b = (const float*)d_in[1];  // (8192,)
    const float* q = (const float*)d_in[2];  // (8192,)
    const float* e = (const float*)d_in[3];  // (8192,)
    const float* M = (const float*)d_in[4];  // (100, 8192)
    float* out = (float*)d_out;              // (256, 100)

    const size_t need = (size_t)BB * NN * sizeof(float) + (BB + CC) * sizeof(float);
    if (ws_size >= need) {
        float* kbuf  = (float*)d_ws;
        float* norms = kbuf + (size_t)BB * NN;
        fire_kernel<<<dim3(NN), dim3(256), 0, stream>>>(x, b, q, e, kbuf);
        norm_kernel<<<dim3(BB + CC), dim3(256), 0, stream>>>(kbuf, M, norms);
        logits_kernel<<<dim3(128), dim3(256), 0, stream>>>(kbuf, M, norms, out);
    } else {
        gls_fused_kernel<<<dim3(BB), dim3(256), 0, stream>>>(x, b, q, e, M, out);
    }
}

// Round 15
// 117.438 us; speedup vs baseline: 6.1760x; 1.3871x over previous
//
#include <hip/hip_runtime.h>
#include <math.h>

// Problem constants: x(256,8192) b,q,e(8192) M(100,8192) out(256,100)
#define NN 8192
#define BB 256
#define CC 100
#define MAX_ITERS 4096
#define CHUNK 10   // classes per logits block

// ---------------------------------------------------------------------------
// Fire kernel, wave = one column x 64 rows (lane = row). Map trajectory is
// wave-uniform; per-lane band checks. Unroll-4 window: exit tests (ballot,
// cycle branch) once per 4 iters. Per-lane a/kk updates stay per-iteration
// (bit-exact); post-fire wasted iters are harmless (a already false).
//
// Cycle fast-forward (bit-exact): when the uniform trajectory repeats a
// previously-survived value, still-active lanes can never fire ->
// kk += MAX_ITERS - it (it = iterations processed). Survivors at the window
// end survived the whole detected cycle segment, so the credit is exact
// regardless of where in the window detection happened.
//
// Locked reference flavor (r10): hoisted IEEE f32 reciprocals rb=1.0f/b,
// rob=1.0f/(1-b); m' = (m<b ? m*rb : (1-m)*rob); separate sub/mul/select
// (no FMA contraction); lo=x-e, hi=x+e exact f32 subs.
// ---------------------------------------------------------------------------
__global__ __launch_bounds__(256) void fire_kernel(
    const float* __restrict__ x, const float* __restrict__ bmap,
    const float* __restrict__ qini, const float* __restrict__ eps,
    float* __restrict__ kout)
{
    const int j    = blockIdx.x;              // column (one per block)
    const int lane = threadIdx.x & 63;
    const int row  = (threadIdx.x & ~63) + lane;   // wave w covers rows 64w..64w+63

    const float bv  = bmap[j];                // uniform across the wave
    const float qv  = qini[j];
    const float ev  = eps[j];
    const float obv = 1.0f - bv;              // exact (Sterbenz)
    const float rb  = 1.0f / bv;              // hoisted IEEE f32 reciprocals
    const float rob = 1.0f / obv;

    const float xv  = x[(size_t)row * NN + j];     // scattered dword load (once)
    const float lov = xv - ev;                // exact f32 subs, same bits as ref
    const float hiv = xv + ev;

    float m = qv, anchor = qv;                // uniform trajectory state
    int   window = 1, steps = 0;
    int   kk = 1;
    bool  a  = (qv != 0.0f);                  // q==0: never fires
    bool  cycseen = false;

    int it = 0;
    while (it < MAX_ITERS) {
        #pragma unroll
        for (int u = 0; u < 4; ++u) {
            const bool  lt = (m < bv);
            const float pa = m * rb;
            const float pb = (1.0f - m) * rob;
            m = lt ? pa : pb;

            cycseen = cycseen || (m == anchor);   // Brent probe
            if (++steps == window) { anchor = m; window <<= 1; steps = 0; }

            const bool o = (m < lov) || (m > hiv);
            a = a && o;
            kk += a ? 1 : 0;
        }
        it += 4;
        if (__ballot(a) == 0ull) break;       // all 64 rows fired
        if (cycseen) {                        // trajectory periodic ->
            kk += a ? (MAX_ITERS - it) : 0;   // survivors never fire (exact)
            break;
        }
    }

    kout[(size_t)row * NN + j] = (float)kk;   // scattered dword store (once)
}

// ---------------------------------------------------------------------------
// Fused logits+norm kernel: block = (row-quad, 10-class chunk), grid 640.
// k rows in registers; k-row norms computed from those registers (f64,
// same partial order as the old norm kernel -> bit-identical); per-class
// M-norm computed alongside the dot (f64, same order as old norm kernel).
// Dot accumulation order identical to the proven r12/r14 kernel.
// ---------------------------------------------------------------------------
__global__ __launch_bounds__(256) void logits_kernel(
    const float* __restrict__ k, const float* __restrict__ M,
    float* __restrict__ out)
{
    __shared__ float  redd[4][4];   // [wave][row] dot partials
    __shared__ double redm[4];      // [wave] msq partials
    __shared__ double redk[4][4];   // [wave][row] k-sumsq partials
    __shared__ float  knsh[4];      // final k-row norms

    const int rq  = blockIdx.x / CHUNK;   // 0..63 row-quad
    const int ch  = blockIdx.x % CHUNK;   // 0..9 class chunk
    const int i0  = rq * 4;
    const int tid = threadIdx.x;
    const int wid = tid >> 6, lane = tid & 63;

    // ---- load 4 k rows into registers (coalesced float4) ----
    float4 kr[4][8];
    #pragma unroll
    for (int r = 0; r < 4; ++r)
        #pragma unroll
        for (int s = 0; s < 8; ++s)
            kr[r][s] = *(const float4*)(k + (size_t)(i0 + r) * NN + s * 1024 + tid * 4);

    // ---- k-row norms (f64), once per block ----
    {
        double ks[4] = {0.0, 0.0, 0.0, 0.0};
        #pragma unroll
        for (int s = 0; s < 8; ++s)
            #pragma unroll
            for (int r = 0; r < 4; ++r) {
                const float4 v = kr[r][s];
                ks[r] += (double)v.x * v.x + (double)v.y * v.y
                       + (double)v.z * v.z + (double)v.w * v.w;
            }
        #pragma unroll
        for (int off = 32; off; off >>= 1)
            #pragma unroll
            for (int r = 0; r < 4; ++r) ks[r] += __shfl_down(ks[r], off, 64);
        if (lane == 0)
            #pragma unroll
            for (int r = 0; r < 4; ++r) redk[wid][r] = ks[r];
        __syncthreads();
        if (tid < 4) {
            const double t = redk[0][tid] + redk[1][tid] + redk[2][tid] + redk[3][tid];
            knsh[tid] = fmaxf((float)sqrt(t), 1e-8f);
        }
        __syncthreads();
    }

    // ---- 10 classes: fused dot (f32, proven order) + M-norm (f64) ----
    for (int c = ch * CHUNK; c < ch * CHUNK + CHUNK; ++c) {
        const float4* Mp = (const float4*)(M + (size_t)c * NN);
        float  acc[4] = {0.0f, 0.0f, 0.0f, 0.0f};
        double msq = 0.0;
        #pragma unroll
        for (int s = 0; s < 8; ++s) {
            const float4 mv = Mp[s * 256 + tid];
            msq += (double)mv.x * mv.x + (double)mv.y * mv.y
                 + (double)mv.z * mv.z + (double)mv.w * mv.w;
            #pragma unroll
            for (int r = 0; r < 4; ++r)
                acc[r] += kr[r][s].x * mv.x + kr[r][s].y * mv.y
                        + kr[r][s].z * mv.z + kr[r][s].w * mv.w;
        }
        #pragma unroll
        for (int off = 32; off; off >>= 1) {
            #pragma unroll
            for (int r = 0; r < 4; ++r) acc[r] += __shfl_down(acc[r], off, 64);
            msq += __shfl_down(msq, off, 64);
        }
        if (lane == 0) {
            #pragma unroll
            for (int r = 0; r < 4; ++r) redd[wid][r] = acc[r];
            redm[wid] = msq;
        }
        __syncthreads();
        if (tid < 4) {
            const double mt = redm[0] + redm[1] + redm[2] + redm[3];
            const float  mn = fmaxf((float)sqrt(mt), 1e-8f);
            const float  d  = redd[0][tid] + redd[1][tid] + redd[2][tid] + redd[3][tid];
            out[(size_t)(i0 + tid) * CC + c] = d / (knsh[tid] * mn);
        }
        __syncthreads();
    }
}

// ===========================================================================
// FALLBACK: round-10 fused kernel, verbatim (proven green), used only if
// ws_size is too small for the k matrix.
// ===========================================================================
__global__ __launch_bounds__(256) void gls_fused_kernel(
    const float* __restrict__ x, const float* __restrict__ bmap,
    const float* __restrict__ qini, const float* __restrict__ eps,
    const float* __restrict__ M, float* __restrict__ out)
{
    __shared__ float k_lds[NN];
    __shared__ double redsh[4];

    const int i   = blockIdx.x;
    const int tid = threadIdx.x;
    const int wid = tid >> 6, lane = tid & 63;

    double sumsq = 0.0;
    for (int s = 0; s < 32; ++s) {
        const int j = tid + 256 * s;
        const float bv = bmap[j];
        const float qv = qini[j];
        const float ev = eps[j];
        const float xv = x[(size_t)i * NN + j];
        const float lov = xv - ev;
        const float hiv = xv + ev;
        const float obv = 1.0f - bv;
        const float rb  = 1.0f / bv;
        const float rob = 1.0f / obv;

        float m  = qv;
        float kk = 1.0f;
        bool  a  = (qv != 0.0f);
        for (int it = 0; a && it < MAX_ITERS; ++it) {
            const bool  lt  = (m < bv);
            const float num = lt ? m  : (1.0f - m);
            const float r   = lt ? rb : rob;
            m = num * r;
            a = (m < lov) || (m > hiv);
            kk += a ? 1.0f : 0.0f;
        }
        k_lds[j] = kk;
        sumsq += (double)kk * (double)kk;
    }

    #pragma unroll
    for (int off = 32; off; off >>= 1) sumsq += __shfl_down(sumsq, off, 64);
    if (lane == 0) redsh[wid] = sumsq;
    __syncthreads();
    const double rn = fmax(sqrt(redsh[0] + redsh[1] + redsh[2] + redsh[3]), 1e-8);

    for (int cc2 = 0; cc2 < 25; ++cc2) {
        const int c = wid * 25 + cc2;
        const float4* Mp = (const float4*)(M + (size_t)c * NN);
        double dot = 0.0, msq = 0.0;
        #pragma unroll 4
        for (int s = 0; s < 32; ++s) {
            const float4 mv = Mp[lane + 64 * s];
            const float4 kv = *(const float4*)(&k_lds[4 * (lane + 64 * s)]);
            dot += (double)kv.x * (double)mv.x + (double)kv.y * (double)mv.y
                 + (double)kv.z * (double)mv.z + (double)kv.w * (double)mv.w;
            msq += (double)mv.x * (double)mv.x + (double)mv.y * (double)mv.y
                 + (double)mv.z * (double)mv.z + (double)mv.w * (double)mv.w;
        }
        #pragma unroll
        for (int off = 32; off; off >>= 1) {
            dot += __shfl_down(dot, off, 64);
            msq += __shfl_down(msq, off, 64);
        }
        if (lane == 0) {
            const double mn = fmax(sqrt(msq), 1e-8);
            out[(size_t)i * CC + c] = (float)(dot / (rn * mn));
        }
    }
}

// ---------------------------------------------------------------------------
extern "C" void kernel_launch(void* const* d_in, const int* in_sizes, int n_in,
                              void* d_out, int out_size, void* d_ws, size_t ws_size,
                              hipStream_t stream) {
    const float* x = (const float*)d_in[0];  // (256, 8192)
    const float* b = (const float*)d_in[1];  // (8192,)
    const float* q = (const float*)d_in[2];  // (8192,)
    const float* e = (const float*)d_in[3];  // (8192,)
    const float* M = (const float*)d_in[4];  // (100, 8192)
    float* out = (float*)d_out;              // (256, 100)

    const size_t need = (size_t)BB * NN * sizeof(float);
    if (ws_size >= need) {
        float* kbuf = (float*)d_ws;
        fire_kernel<<<dim3(NN), dim3(256), 0, stream>>>(x, b, q, e, kbuf);
        logits_kernel<<<dim3((BB / 4) * CHUNK), dim3(256), 0, stream>>>(kbuf, M, out);
    } else {
        gls_fused_kernel<<<dim3(BB), dim3(256), 0, stream>>>(x, b, q, e, M, out);
    }
}